// Round 3
// baseline (1029.308 us; speedup 1.0000x reference)
//
#include <hip/hip_runtime.h>

#define BSZ 256
#define CCH 512
#define HW_ 81
#define DD 9
#define CH 41472   /* CCH*HW_ */
#define NT 512

/* ws layout (floats) */
#define WS_W1T   0        /* [162][81] folded+transposed se_att_w1 */
#define WS_TSE   13122    /* [81]  folded se_att bias */
#define WS_S2    13203    /* [512] sa_key bn scale */
#define WS_T2    13715    /* [512] sa_key bn bias */
#define WS_W1S   14227    /* [512][16] folded sa_att_w1 */
#define WS_T1    22419    /* [512] folded sa_att bias */
#define WS_TOTAL 22931

__device__ __forceinline__ float bf2f(unsigned short u) {
    return __uint_as_float(((unsigned int)u) << 16);
}
__device__ __forceinline__ unsigned short f2bf(float f) {
    unsigned int u = __float_as_uint(f);
    return (unsigned short)((u + 0x7FFFu + ((u >> 16) & 1u)) >> 16);
}

__global__ void prep_kernel(const float* __restrict__ se_att_w1,  // 81*162
                            const float* __restrict__ se_att_bn,  // 4*81
                            const float* __restrict__ sa_key_bn,  // 4*512
                            const float* __restrict__ sa_att_w1,  // 512*16
                            const float* __restrict__ sa_att_bn,  // 4*512
                            float* __restrict__ ws) {
    int idx = blockIdx.x * blockDim.x + threadIdx.x;
    if (idx < 13122) {
        int r = idx / 81, o = idx % 81;
        float g = se_att_bn[o], v = se_att_bn[243 + o];
        float s = g * rsqrtf(v + 1e-5f);
        ws[WS_W1T + idx] = se_att_w1[o * 162 + r] * s;
    } else if (idx < 13203) {
        int o = idx - 13122;
        float g = se_att_bn[o], b = se_att_bn[81 + o], m = se_att_bn[162 + o], v = se_att_bn[243 + o];
        float s = g * rsqrtf(v + 1e-5f);
        ws[WS_TSE + o] = b - m * s;
    } else if (idx < 13715) {
        int c = idx - 13203;
        float g = sa_key_bn[c], v = sa_key_bn[1536 + c];
        ws[WS_S2 + c] = g * rsqrtf(v + 1e-5f);
    } else if (idx < 14227) {
        int c = idx - 13715;
        float g = sa_key_bn[c], b = sa_key_bn[512 + c], m = sa_key_bn[1024 + c], v = sa_key_bn[1536 + c];
        float s = g * rsqrtf(v + 1e-5f);
        ws[WS_T2 + c] = b - m * s;
    } else if (idx < 22419) {
        int e = idx - 14227;
        int o = e >> 4;
        float g = sa_att_bn[o], v = sa_att_bn[1536 + o];
        float s = g * rsqrtf(v + 1e-5f);
        ws[WS_W1S + e] = sa_att_w1[e] * s;
    } else if (idx < WS_TOTAL) {
        int o = idx - 22419;
        float g = sa_att_bn[o], b = sa_att_bn[512 + o], m = sa_att_bn[1024 + o], v = sa_att_bn[1536 + o];
        float s = g * rsqrtf(v + 1e-5f);
        ws[WS_T1 + o] = b - m * s;
    }
}

// P2 is chunked (3 x 27 outputs) so the live accumulator set is ~70 VGPRs:
// round 1/2 showed the compiler caps at 128 VGPRs regardless of
// __launch_bounds__ and spilled acc[81] -> 1.25 GB scratch HBM traffic.
__global__ __launch_bounds__(NT) void fused_kernel(
    const float* __restrict__ x,
    const float* __restrict__ alpha,
    const float* __restrict__ sa_key_w,   // 512*9
    const float* __restrict__ sa_att_w2,  // 64*8
    const float* __restrict__ sa_att_b2,  // 64
    const float* __restrict__ se_key_w,   // 81*9
    const float* __restrict__ se_key_b,   // 81
    const float* __restrict__ se_att_w2,  // 9*81
    const float* __restrict__ se_att_b2,  // 9
    const float* __restrict__ se_val_w,   // 512*9
    const float* __restrict__ se_val_b,   // 512
    const float* __restrict__ ws,
    float* __restrict__ out)
{
    __shared__ __align__(16) unsigned short xb[CH];   // 82944 B, x[b] bf16, channel-major flat
    __shared__ float A2buf[64 * HW_];                 // 20736 B
    __shared__ float attbuf[DD * CCH];                // 18432 B
    __shared__ float wseb[HW_ * DD];                  //  2916 B
    __shared__ float bseb[HW_];                       //   324 B
    __shared__ unsigned short wvb[CCH * DD];          //  9216 B
    __shared__ unsigned short wkb[CCH * DD];          //  9216 B
    __shared__ float bvb[CCH];                        //  2048 B
    __shared__ float s2b[CCH];                        //  2048 B
    __shared__ float t2b[CCH];                        //  2048 B
    /* total ~149928 B < 163840 B */

    const int b = blockIdx.x;
    const int t = threadIdx.x;
    const float av = alpha[0];

    // ================= P0: stage x and tables =================
    {
        const float4* x4 = (const float4*)(x + (size_t)b * CH);
        for (int v = t; v < CH / 4; v += NT) {
            float4 q = x4[v];
            ushort4 s4;
            s4.x = f2bf(q.x); s4.y = f2bf(q.y); s4.z = f2bf(q.z); s4.w = f2bf(q.w);
            *(ushort4*)(&xb[4 * v]) = s4;
        }
        for (int v = t; v < HW_ * DD; v += NT) wseb[v] = se_key_w[v];
        if (t < HW_) bseb[t] = se_key_b[t];
        for (int v = t; v < CCH * DD; v += NT) {
            wvb[v] = f2bf(se_val_w[v]);
            wkb[v] = f2bf(sa_key_w[v]);
        }
        if (t < CCH) {
            bvb[t] = se_val_b[t];
            s2b[t] = ws[WS_S2 + t];
            t2b[t] = ws[WS_T2 + t];
        }
    }
    __syncthreads();

    // ================= P1: SaMCA attention -> A2buf =================
    {
        const int g = t >> 3, sub = t & 7;
        const float* w1sg = ws + WS_W1S;
        const float* t1g = ws + WS_T1;
        const float b2g = sa_att_b2[g];
        float a2v[11];
        #pragma unroll
        for (int k = 0; k < 11; ++k) {
            int p = sub + 8 * k;
            float res = -1e30f;
            if (p < 81) {
                int y = p / 9, xx = p - (p / 9) * 9;
                float kv[8], xv[8];
                #pragma unroll
                for (int j = 0; j < 8; ++j) {
                    int c = 8 * g + j;
                    float conv = 0.f;
                    #pragma unroll
                    for (int ky = 0; ky < 3; ++ky) {
                        int yy = y + ky - 1;
                        if (yy < 0 || yy > 8) continue;
                        #pragma unroll
                        for (int kx = 0; kx < 3; ++kx) {
                            int xc = xx + kx - 1;
                            if (xc < 0 || xc > 8) continue;
                            conv = fmaf(bf2f(xb[c * 81 + yy * 9 + xc]),
                                        bf2f(wkb[c * 9 + ky * 3 + kx]), conv);
                        }
                    }
                    float k1sv = conv * s2b[c] + t2b[c];
                    kv[j] = fmaxf(k1sv, 0.f);
                    xv[j] = bf2f(xb[c * 81 + p]);
                }
                float s = b2g;
                #pragma unroll
                for (int j = 0; j < 8; ++j) {
                    int o = 8 * g + j;
                    float z = t1g[o];
                    const float* w1o = w1sg + o * 16;
                    #pragma unroll
                    for (int l = 0; l < 16; ++l) {
                        float in = (l & 1) ? xv[l >> 1] : kv[l >> 1];
                        z = fmaf(w1o[l], in, z);
                    }
                    z = fmaxf(z, 0.f);
                    s = fmaf(sa_att_w2[g * 8 + j], z, s);
                }
                res = s;
            }
            a2v[k] = res;
        }
        // softmax over the 81 pixels, distributed across the 8-lane octet
        float m = a2v[0];
        #pragma unroll
        for (int k = 1; k < 11; ++k) m = fmaxf(m, a2v[k]);
        #pragma unroll
        for (int off = 1; off < 8; off <<= 1) m = fmaxf(m, __shfl_xor(m, off, 64));
        float ls = 0.f;
        float ev[11];
        #pragma unroll
        for (int k = 0; k < 11; ++k) { ev[k] = __expf(a2v[k] - m); ls += ev[k]; }
        #pragma unroll
        for (int off = 1; off < 8; off <<= 1) ls += __shfl_xor(ls, off, 64);
        float inv = 1.f / ls;
        #pragma unroll
        for (int k = 0; k < 11; ++k) {
            int p = sub + 8 * k;
            if (p < 81) A2buf[g * 81 + p] = ev[k] * inv;
        }
    }

    // ================= P2: SeMCA attention -> attbuf =================
    // kq[r][j] = (r<81) ? x.flat[r*512+j] : K1.flat[(r-81)*512+j]
    // 3 chunks of 27 outputs, ad[9] folded incrementally -> no acc[81] spill.
    {
        const int j = t;
        const float* w1t = ws + WS_W1T;
        const float* tse = ws + WS_TSE;
        float ad[9];
        #pragma unroll
        for (int d = 0; d < 9; ++d) ad[d] = se_att_b2[d];
        #pragma unroll 1
        for (int chunk = 0; chunk < 3; ++chunk) {
            const int obase = chunk * 27;
            float acc[27];
            #pragma unroll
            for (int o = 0; o < 27; ++o) acc[o] = 0.f;
            #pragma unroll 2
            for (int r = 0; r < 162; ++r) {
                float Bval;
                if (r < 81) {
                    Bval = bf2f(xb[r * 512 + j]);
                } else {
                    int e = (r - 81) * 512 + j;
                    int i = e / 81;
                    int p = e - i * 81;
                    float s = bseb[p];
                    #pragma unroll
                    for (int tau = 0; tau < 9; ++tau) {
                        int flat = e + (tau - 4) * 81;
                        if (flat >= 0 && flat < CH) s = fmaf(bf2f(xb[flat]), wseb[p * 9 + tau], s);
                    }
                    Bval = s;
                }
                const float* wr = w1t + r * 81 + obase;  // wave-uniform -> scalar loads
                #pragma unroll
                for (int o = 0; o < 27; ++o) acc[o] = fmaf(wr[o], Bval, acc[o]);
            }
            #pragma unroll
            for (int o = 0; o < 27; ++o) {
                float z = fmaxf(acc[o] + tse[obase + o], 0.f);
                #pragma unroll
                for (int d = 0; d < 9; ++d)
                    ad[d] = fmaf(se_att_w2[d * 81 + obase + o], z, ad[d]);
            }
        }
        float m = ad[0];
        #pragma unroll
        for (int d = 1; d < 9; ++d) m = fmaxf(m, ad[d]);
        float ls = 0.f;
        #pragma unroll
        for (int d = 0; d < 9; ++d) { ad[d] = __expf(ad[d] - m); ls += ad[d]; }
        float inv = 1.f / ls;
        #pragma unroll
        for (int d = 0; d < 9; ++d) attbuf[d * 512 + j] = ad[d] * inv;
    }
    __syncthreads();

    // ================= P3: final combine =================
    // thread = (slab, pixel); rolling 9-deep rings of v (se_val dw conv) and k1s
    if (t < 486) {
        const int slab = t / 81;
        const int p = t - slab * 81;
        const int y = p / 9, xx = p - (p / 9) * 9;
        float wse_r[9];
        #pragma unroll
        for (int tau = 0; tau < 9; ++tau) wse_r[tau] = wseb[p * 9 + tau];
        const float bse_r = bseb[p];
        const int cbeg = slab * 86;
        const int cend = (cbeg + 86 < 512) ? (cbeg + 86) : 512;
        float* outb = out + (size_t)b * CH;

        auto computeVK = [&](int cc, float& vv, float& kk) {
            if (cc < 0 || cc >= 512) { vv = 0.f; kk = 0.f; return; }
            float sv = 0.f, sk = 0.f;
            #pragma unroll
            for (int ky = 0; ky < 3; ++ky) {
                int yy = y + ky - 1;
                if (yy < 0 || yy > 8) continue;
                #pragma unroll
                for (int kx = 0; kx < 3; ++kx) {
                    int xc = xx + kx - 1;
                    if (xc < 0 || xc > 8) continue;
                    float xvv = bf2f(xb[cc * 81 + yy * 9 + xc]);
                    sv = fmaf(xvv, bf2f(wvb[cc * 9 + ky * 3 + kx]), sv);
                    sk = fmaf(xvv, bf2f(wkb[cc * 9 + ky * 3 + kx]), sk);
                }
            }
            vv = sv + bvb[cc];
            kk = fmaxf(sk * s2b[cc] + t2b[cc], 0.f);
        };

        float vr[9], kr[9];
        #pragma unroll
        for (int d = 0; d < 9; ++d) computeVK(cbeg + d - 4, vr[d], kr[d]);

        for (int c = cbeg; c < cend; ++c) {
            float o1 = 0.f;
            #pragma unroll
            for (int d = 0; d < 9; ++d) o1 = fmaf(vr[d], attbuf[d * 512 + c], o1);
            float k1se = bse_r;
            #pragma unroll
            for (int tau = 0; tau < 9; ++tau) {
                int ci = c + tau - 4;
                if (ci >= 0 && ci < 512) k1se = fmaf(bf2f(xb[ci * 81 + p]), wse_r[tau], k1se);
            }
            float xcv = bf2f(xb[c * 81 + p]);
            float out2 = kr[4] + A2buf[(c >> 3) * 81 + p] * xcv;
            outb[c * 81 + p] = av * (o1 + k1se) + (1.f - av) * out2;
            #pragma unroll
            for (int d = 0; d < 8; ++d) { vr[d] = vr[d + 1]; kr[d] = kr[d + 1]; }
            float nv, nk;
            computeVK(c + 5, nv, nk);
            vr[8] = nv; kr[8] = nk;
        }
    }
}

extern "C" void kernel_launch(void* const* d_in, const int* in_sizes, int n_in,
                              void* d_out, int out_size, void* d_ws, size_t ws_size,
                              hipStream_t stream) {
    const float* x          = (const float*)d_in[0];
    const float* alpha      = (const float*)d_in[1];
    const float* sa_key_w   = (const float*)d_in[2];
    const float* sa_key_bn  = (const float*)d_in[3];
    const float* sa_att_w1  = (const float*)d_in[4];
    const float* sa_att_bn  = (const float*)d_in[5];
    const float* sa_att_w2  = (const float*)d_in[6];
    const float* sa_att_b2  = (const float*)d_in[7];
    const float* se_key_w   = (const float*)d_in[8];
    const float* se_key_b   = (const float*)d_in[9];
    const float* se_att_w1  = (const float*)d_in[10];
    const float* se_att_bn  = (const float*)d_in[11];
    const float* se_att_w2  = (const float*)d_in[12];
    const float* se_att_b2  = (const float*)d_in[13];
    const float* se_val_w   = (const float*)d_in[14];
    const float* se_val_b   = (const float*)d_in[15];
    float* ws = (float*)d_ws;
    float* outp = (float*)d_out;

    prep_kernel<<<(WS_TOTAL + 255) / 256, 256, 0, stream>>>(
        se_att_w1, se_att_bn, sa_key_bn, sa_att_w1, sa_att_bn, ws);
    fused_kernel<<<BSZ, NT, 0, stream>>>(
        x, alpha, sa_key_w, sa_att_w2, sa_att_b2,
        se_key_w, se_key_b, se_att_w2, se_att_b2,
        se_val_w, se_val_b, ws, outp);
}

// Round 4
// 738.378 us; speedup vs baseline: 1.3940x; 1.3940x over previous
//
#include <hip/hip_runtime.h>

#define BSZ 256
#define CCH 512
#define HW_ 81
#define DD 9
#define CH 41472   /* CCH*HW_ */

/* ws layout (floats) */
#define WS_W1T   0        /* [162][81] folded+transposed se_att_w1 */
#define WS_TSE   13122    /* [81]  folded se_att bias */
#define WS_S2    13203    /* [512] sa_key bn scale */
#define WS_T2    13715    /* [512] sa_key bn bias */
#define WS_W1S   14227    /* [512][16] folded sa_att_w1 */
#define WS_T1    22419    /* [512] folded sa_att bias */
#define WS_A2    22932    /* [256][64][81] SaMCA attention */
#define WS_ATT   1350036  /* [256][9][512] SeMCA attention */
#define WS_TOTALP 22931   /* params region end */

__device__ __forceinline__ float bf2f(unsigned short u) {
    return __uint_as_float(((unsigned int)u) << 16);
}
__device__ __forceinline__ unsigned short f2bf(float f) {
    unsigned int u = __float_as_uint(f);
    return (unsigned short)((u + 0x7FFFu + ((u >> 16) & 1u)) >> 16);
}

__global__ void prep_kernel(const float* __restrict__ se_att_w1,  // 81*162
                            const float* __restrict__ se_att_bn,  // 4*81
                            const float* __restrict__ sa_key_bn,  // 4*512
                            const float* __restrict__ sa_att_w1,  // 512*16
                            const float* __restrict__ sa_att_bn,  // 4*512
                            float* __restrict__ ws) {
    int idx = blockIdx.x * blockDim.x + threadIdx.x;
    if (idx < 13122) {
        int r = idx / 81, o = idx % 81;
        float g = se_att_bn[o], v = se_att_bn[243 + o];
        float s = g * rsqrtf(v + 1e-5f);
        ws[WS_W1T + idx] = se_att_w1[o * 162 + r] * s;
    } else if (idx < 13203) {
        int o = idx - 13122;
        float g = se_att_bn[o], b = se_att_bn[81 + o], m = se_att_bn[162 + o], v = se_att_bn[243 + o];
        float s = g * rsqrtf(v + 1e-5f);
        ws[WS_TSE + o] = b - m * s;
    } else if (idx < 13715) {
        int c = idx - 13203;
        float g = sa_key_bn[c], v = sa_key_bn[1536 + c];
        ws[WS_S2 + c] = g * rsqrtf(v + 1e-5f);
    } else if (idx < 14227) {
        int c = idx - 13715;
        float g = sa_key_bn[c], b = sa_key_bn[512 + c], m = sa_key_bn[1024 + c], v = sa_key_bn[1536 + c];
        float s = g * rsqrtf(v + 1e-5f);
        ws[WS_T2 + c] = b - m * s;
    } else if (idx < 22419) {
        int e = idx - 14227;
        int o = e >> 4;
        float g = sa_att_bn[o], v = sa_att_bn[1536 + o];
        float s = g * rsqrtf(v + 1e-5f);
        ws[WS_W1S + e] = sa_att_w1[e] * s;
    } else if (idx < WS_TOTALP) {
        int o = idx - 22419;
        float g = sa_att_bn[o], b = sa_att_bn[512 + o], m = sa_att_bn[1024 + o], v = sa_att_bn[1536 + o];
        float s = g * rsqrtf(v + 1e-5f);
        ws[WS_T1 + o] = b - m * s;
    }
}

// ============== Kernel A: attention (P1 + P2), one block per batch ==========
__global__ __launch_bounds__(512) void attn_kernel(
    const float* __restrict__ x,
    const float* __restrict__ sa_key_w,   // 512*9
    const float* __restrict__ sa_att_w2,  // 64*8
    const float* __restrict__ sa_att_b2,  // 64
    const float* __restrict__ se_key_w,   // 81*9
    const float* __restrict__ se_key_b,   // 81
    const float* __restrict__ se_att_w2,  // 9*81
    const float* __restrict__ se_att_b2,  // 9
    float* __restrict__ ws)
{
    __shared__ __align__(16) unsigned short xb[CH];   // 82944 B
    __shared__ unsigned short wkb[CCH * DD];          //  9216 B
    __shared__ float wseb[HW_ * DD];                  //  2916 B
    __shared__ float bseb[HW_];                       //   324 B
    __shared__ float s2b[CCH];                        //  2048 B
    __shared__ float t2b[CCH];                        //  2048 B
    /* ~99.5 KB */

    const int b = blockIdx.x;
    const int t = threadIdx.x;

    // stage
    {
        const float4* x4 = (const float4*)(x + (size_t)b * CH);
        for (int v = t; v < CH / 4; v += 512) {
            float4 q = x4[v];
            ushort4 s4;
            s4.x = f2bf(q.x); s4.y = f2bf(q.y); s4.z = f2bf(q.z); s4.w = f2bf(q.w);
            *(ushort4*)(&xb[4 * v]) = s4;
        }
        for (int v = t; v < CCH * DD; v += 512) wkb[v] = f2bf(sa_key_w[v]);
        for (int v = t; v < HW_ * DD; v += 512) wseb[v] = se_key_w[v];
        if (t < HW_) bseb[t] = se_key_b[t];
        if (t < CCH) { s2b[t] = ws[WS_S2 + t]; t2b[t] = ws[WS_T2 + t]; }
    }
    __syncthreads();

    // ---- P1: SaMCA attention -> ws A2 ----
    {
        const int g = t >> 3, sub = t & 7;
        const float* w1sg = ws + WS_W1S;
        const float* t1g = ws + WS_T1;
        const float b2g = sa_att_b2[g];
        float a2v[11];
        #pragma unroll
        for (int k = 0; k < 11; ++k) {
            int p = sub + 8 * k;
            float res = -1e30f;
            if (p < 81) {
                int y = p / 9, xx = p - (p / 9) * 9;
                float z[8];
                #pragma unroll
                for (int o = 0; o < 8; ++o) z[o] = t1g[8 * g + o];
                #pragma unroll
                for (int j = 0; j < 8; ++j) {
                    int c = 8 * g + j;
                    float conv = 0.f;
                    #pragma unroll
                    for (int ky = 0; ky < 3; ++ky) {
                        int yy = y + ky - 1;
                        if (yy < 0 || yy > 8) continue;
                        #pragma unroll
                        for (int kx = 0; kx < 3; ++kx) {
                            int xc = xx + kx - 1;
                            if (xc < 0 || xc > 8) continue;
                            conv = fmaf(bf2f(xb[c * 81 + yy * 9 + xc]),
                                        bf2f(wkb[c * 9 + ky * 3 + kx]), conv);
                        }
                    }
                    float kv = fmaxf(conv * s2b[c] + t2b[c], 0.f);
                    float xv = bf2f(xb[c * 81 + p]);
                    #pragma unroll
                    for (int o = 0; o < 8; ++o) {
                        const float* w1o = w1sg + (8 * g + o) * 16;
                        z[o] = fmaf(w1o[2 * j], kv, z[o]);
                        z[o] = fmaf(w1o[2 * j + 1], xv, z[o]);
                    }
                }
                float s = b2g;
                #pragma unroll
                for (int o = 0; o < 8; ++o)
                    s = fmaf(sa_att_w2[g * 8 + o], fmaxf(z[o], 0.f), s);
                res = s;
            }
            a2v[k] = res;
        }
        float m = a2v[0];
        #pragma unroll
        for (int k = 1; k < 11; ++k) m = fmaxf(m, a2v[k]);
        #pragma unroll
        for (int off = 1; off < 8; off <<= 1) m = fmaxf(m, __shfl_xor(m, off, 64));
        float ls = 0.f;
        float ev[11];
        #pragma unroll
        for (int k = 0; k < 11; ++k) { ev[k] = __expf(a2v[k] - m); ls += ev[k]; }
        #pragma unroll
        for (int off = 1; off < 8; off <<= 1) ls += __shfl_xor(ls, off, 64);
        float inv = 1.f / ls;
        float* a2out = ws + WS_A2 + (size_t)b * 5184;
        #pragma unroll
        for (int k = 0; k < 11; ++k) {
            int p = sub + 8 * k;
            if (p < 81) a2out[g * 81 + p] = ev[k] * inv;
        }
    }

    // ---- P2: SeMCA attention -> ws ATT ----
    // kq[r][j] = (r<81) ? x.flat[r*512+j] : K1.flat[(r-81)*512+j]
    {
        const int j = t;
        const float* w1t = ws + WS_W1T;
        const float* tse = ws + WS_TSE;
        float ad[9];
        #pragma unroll
        for (int d = 0; d < 9; ++d) ad[d] = se_att_b2[d];
        #pragma unroll 1
        for (int chunk = 0; chunk < 3; ++chunk) {
            const int obase = chunk * 27;
            float acc[27];
            #pragma unroll
            for (int o = 0; o < 27; ++o) acc[o] = 0.f;
            #pragma unroll 2
            for (int r = 0; r < 162; ++r) {
                float Bval;
                if (r < 81) {
                    Bval = bf2f(xb[r * 512 + j]);
                } else {
                    int e = (r - 81) * 512 + j;
                    int i = e / 81;
                    int p = e - i * 81;
                    float s = bseb[p];
                    #pragma unroll
                    for (int tau = 0; tau < 9; ++tau) {
                        int flat = e + (tau - 4) * 81;
                        if (flat >= 0 && flat < CH) s = fmaf(bf2f(xb[flat]), wseb[p * 9 + tau], s);
                    }
                    Bval = s;
                }
                const float* wr = w1t + r * 81 + obase;  // wave-uniform -> scalar loads
                #pragma unroll
                for (int o = 0; o < 27; ++o) acc[o] = fmaf(wr[o], Bval, acc[o]);
            }
            #pragma unroll
            for (int o = 0; o < 27; ++o) {
                float z = fmaxf(acc[o] + tse[obase + o], 0.f);
                #pragma unroll
                for (int d = 0; d < 9; ++d)
                    ad[d] = fmaf(se_att_w2[d * 81 + obase + o], z, ad[d]);
            }
        }
        float m = ad[0];
        #pragma unroll
        for (int d = 1; d < 9; ++d) m = fmaxf(m, ad[d]);
        float ls = 0.f;
        #pragma unroll
        for (int d = 0; d < 9; ++d) { ad[d] = __expf(ad[d] - m); ls += ad[d]; }
        float inv = 1.f / ls;
        float* attout = ws + WS_ATT + (size_t)b * 4608;
        #pragma unroll
        for (int d = 0; d < 9; ++d) attout[d * 512 + j] = ad[d] * inv;
    }
}

// ============== Kernel B: combine, block = (batch, 64-channel tile) =========
__global__ __launch_bounds__(256) void combine_kernel(
    const float* __restrict__ x,
    const float* __restrict__ alpha,
    const float* __restrict__ sa_key_w,   // 512*9
    const float* __restrict__ se_key_w,   // 81*9
    const float* __restrict__ se_key_b,   // 81
    const float* __restrict__ se_val_w,   // 512*9
    const float* __restrict__ se_val_b,   // 512
    const float* __restrict__ ws,
    float* __restrict__ out)
{
    __shared__ float xs[72 * 81];   // channels c0-4 .. c0+67 (zero-pad OOB)
    __shared__ float vs[72 * 81];   // depthwise-v plane (zero OOB, matches pad_v)
    __shared__ float wvL[72 * 9];
    __shared__ float bvL[72];
    __shared__ float wkL[64 * 9];
    __shared__ float s2L[64];
    __shared__ float t2L[64];
    __shared__ float wseL[81 * 9];
    __shared__ float bseL[81];
    __shared__ float attL[9 * 64];
    __shared__ float a2L[8 * 81];
    /* ~60.5 KB */

    const int bid = blockIdx.x;
    const int b = bid >> 3;
    const int tile = bid & 7;
    const int c0 = tile * 64;
    const int t = threadIdx.x;
    const int f0 = (c0 - 4) * 81;

    for (int idx = t; idx < 5832; idx += 256) {
        int g = f0 + idx;
        xs[idx] = (g >= 0 && g < CH) ? x[(size_t)b * CH + g] : 0.f;
    }
    for (int idx = t; idx < 648; idx += 256) {
        int cc = c0 - 4 + idx / 9;
        wvL[idx] = (cc >= 0 && cc < 512) ? se_val_w[cc * 9 + idx % 9] : 0.f;
    }
    if (t < 72) {
        int cc = c0 - 4 + t;
        bvL[t] = (cc >= 0 && cc < 512) ? se_val_b[cc] : 0.f;
    }
    for (int idx = t; idx < 576; idx += 256) wkL[idx] = sa_key_w[c0 * 9 + idx];
    if (t < 64) { s2L[t] = ws[WS_S2 + c0 + t]; t2L[t] = ws[WS_T2 + c0 + t]; }
    for (int idx = t; idx < 729; idx += 256) wseL[idx] = se_key_w[idx];
    if (t < 81) bseL[t] = se_key_b[t];
    for (int idx = t; idx < 576; idx += 256)
        attL[idx] = ws[WS_ATT + (size_t)b * 4608 + (idx >> 6) * 512 + c0 + (idx & 63)];
    for (int idx = t; idx < 648; idx += 256)
        a2L[idx] = ws[WS_A2 + (size_t)b * 5184 + tile * 648 + idx];
    __syncthreads();

    // depthwise-v plane (3x3 conv + bias), zero for OOB channels (= pad_v)
    for (int idx = t; idx < 5832; idx += 256) {
        int i = idx / 81, p = idx - 81 * i;
        int cc = c0 - 4 + i;
        float r = 0.f;
        if (cc >= 0 && cc < 512) {
            int y = p / 9, xx = p - 9 * (p / 9);
            float s = 0.f;
            #pragma unroll
            for (int ky = 0; ky < 3; ++ky) {
                int yy = y + ky - 1;
                if (yy < 0 || yy > 8) continue;
                #pragma unroll
                for (int kx = 0; kx < 3; ++kx) {
                    int xc = xx + kx - 1;
                    if (xc < 0 || xc > 8) continue;
                    s = fmaf(xs[i * 81 + yy * 9 + xc], wvL[i * 9 + ky * 3 + kx], s);
                }
            }
            r = s + bvL[i];
        }
        vs[idx] = r;
    }
    __syncthreads();

    const float av = alpha[0];
    float* outb = out + (size_t)b * CH + (size_t)c0 * 81;
    #pragma unroll 1
    for (int e = t; e < 5184; e += 256) {
        int cl = e / 81, p = e - 81 * cl;
        int y = p / 9, xx = p - 9 * y;
        // spatial key (3x3 dw conv -> bn -> relu)
        float sk = 0.f;
        #pragma unroll
        for (int ky = 0; ky < 3; ++ky) {
            int yy = y + ky - 1;
            if (yy < 0 || yy > 8) continue;
            #pragma unroll
            for (int kx = 0; kx < 3; ++kx) {
                int xc = xx + kx - 1;
                if (xc < 0 || xc > 8) continue;
                sk = fmaf(xs[(cl + 4) * 81 + yy * 9 + xc], wkL[cl * 9 + ky * 3 + kx], sk);
            }
        }
        float k1s = fmaxf(sk * s2L[cl] + t2L[cl], 0.f);
        // spectral attention combine
        float o1 = 0.f;
        #pragma unroll
        for (int d = 0; d < 9; ++d)
            o1 = fmaf(vs[(cl + d) * 81 + p], attL[d * 64 + cl], o1);
        // spectral key value (k1) added to out1
        float k1se = bseL[p];
        #pragma unroll
        for (int tau = 0; tau < 9; ++tau)
            k1se = fmaf(xs[(cl + tau) * 81 + p], wseL[p * 9 + tau], k1se);
        float out2 = k1s + a2L[(cl >> 3) * 81 + p] * xs[(cl + 4) * 81 + p];
        outb[cl * 81 + p] = av * (o1 + k1se) + (1.f - av) * out2;
    }
}

extern "C" void kernel_launch(void* const* d_in, const int* in_sizes, int n_in,
                              void* d_out, int out_size, void* d_ws, size_t ws_size,
                              hipStream_t stream) {
    const float* x          = (const float*)d_in[0];
    const float* alpha      = (const float*)d_in[1];
    const float* sa_key_w   = (const float*)d_in[2];
    const float* sa_key_bn  = (const float*)d_in[3];
    const float* sa_att_w1  = (const float*)d_in[4];
    const float* sa_att_bn  = (const float*)d_in[5];
    const float* sa_att_w2  = (const float*)d_in[6];
    const float* sa_att_b2  = (const float*)d_in[7];
    const float* se_key_w   = (const float*)d_in[8];
    const float* se_key_b   = (const float*)d_in[9];
    const float* se_att_w1  = (const float*)d_in[10];
    const float* se_att_bn  = (const float*)d_in[11];
    const float* se_att_w2  = (const float*)d_in[12];
    const float* se_att_b2  = (const float*)d_in[13];
    const float* se_val_w   = (const float*)d_in[14];
    const float* se_val_b   = (const float*)d_in[15];
    float* ws = (float*)d_ws;
    float* outp = (float*)d_out;

    prep_kernel<<<(WS_TOTALP + 255) / 256, 256, 0, stream>>>(
        se_att_w1, se_att_bn, sa_key_bn, sa_att_w1, sa_att_bn, ws);
    attn_kernel<<<BSZ, 512, 0, stream>>>(
        x, sa_key_w, sa_att_w2, sa_att_b2,
        se_key_w, se_key_b, se_att_w2, se_att_b2, ws);
    combine_kernel<<<BSZ * 8, 256, 0, stream>>>(
        x, alpha, sa_key_w, se_key_w, se_key_b, se_val_w, se_val_b, ws, outp);
}